// Round 2
// baseline (996.554 us; speedup 1.0000x reference)
//
#include <hip/hip_runtime.h>

#define FIN 512
#define FHID 16
#define FOUT 40
#define KC 16

// ---------------- CSR build ----------------

__global__ void k_count(const int* __restrict__ dst, int* __restrict__ cnt, int E) {
    int e = blockIdx.x * blockDim.x + threadIdx.x;
    if (e < E) atomicAdd(&cnt[dst[e]], 1);
}

// single-block exclusive scan of cnt -> row; also writes cursor=row and dinv=rsqrt(cnt+1)
__global__ __launch_bounds__(1024) void k_scan(const int* __restrict__ cnt,
                                               int* __restrict__ row,
                                               int* __restrict__ cursor,
                                               float* __restrict__ dinv, int n) {
    __shared__ int part[1024];
    int t = threadIdx.x;
    int C = (n + 1023) >> 10;
    int lo = t * C;
    int hi = lo + C; if (hi > n) hi = n; if (lo > n) lo = n;
    int s = 0;
    for (int i = lo; i < hi; ++i) s += cnt[i];
    part[t] = s;
    __syncthreads();
    // Hillis-Steele inclusive scan over 1024 partials
    for (int off = 1; off < 1024; off <<= 1) {
        int v = (t >= off) ? part[t - off] : 0;
        __syncthreads();
        part[t] += v;
        __syncthreads();
    }
    int base = (t == 0) ? 0 : part[t - 1];
    for (int i = lo; i < hi; ++i) {
        int c = cnt[i];
        row[i] = base;
        cursor[i] = base;
        dinv[i] = rsqrtf((float)(c + 1));  // +1 self-loop
        base += c;
    }
}

__global__ void k_fill(const int* __restrict__ src, const int* __restrict__ dst,
                       int* __restrict__ cursor, int* __restrict__ srcs_sorted, int E) {
    int e = blockIdx.x * blockDim.x + threadIdx.x;
    if (e >= E) return;
    int p = atomicAdd(&cursor[dst[e]], 1);
    srcs_sorted[p] = src[e];
}

// ---------------- layer 1 GEMM: g = (x @ W1) * dinv ----------------

__global__ __launch_bounds__(128) void k_gemm1(const float* __restrict__ x,
                                               const float* __restrict__ W1,
                                               const float* __restrict__ dinv,
                                               float* __restrict__ g, int n) {
    __shared__ float Wl[FIN * FHID];      // 32 KiB
    __shared__ float xt[128][KC + 1];     // 8.7 KiB, pad -> stride 17 (==1 mod 32, free alias)
    {
        const float4* Wv = reinterpret_cast<const float4*>(W1);
        float4* Lv = reinterpret_cast<float4*>(Wl);
        for (int i = threadIdx.x; i < FIN * FHID / 4; i += 128) Lv[i] = Wv[i];
    }

    int t = threadIdx.x;
    int rowbase = blockIdx.x * 128;

    float acc[FHID];
#pragma unroll
    for (int o = 0; o < FHID; ++o) acc[o] = 0.0f;

#pragma unroll 1
    for (int kc = 0; kc < FIN / KC; ++kc) {
        __syncthreads();  // (also covers Wl readiness on first iter)
        // stage 128 rows x KC floats, coalesced: 512 float4, 4 per thread
#pragma unroll
        for (int j = 0; j < 4; ++j) {
            int v = t + j * 128;
            int r = v >> 2;       // KC/4 = 4 float4 per row
            int c4 = v & 3;
            int grow = rowbase + r;
            float4 xv = make_float4(0.f, 0.f, 0.f, 0.f);
            if (grow < n)
                xv = *reinterpret_cast<const float4*>(&x[(size_t)grow * FIN + kc * KC + c4 * 4]);
            *reinterpret_cast<float4*>(&xt[r][c4 * 4]) = xv;
        }
        __syncthreads();
#pragma unroll
        for (int k = 0; k < KC; ++k) {
            float xs = xt[t][k];
            const float* wrow = &Wl[(kc * KC + k) * FHID];
#pragma unroll
            for (int o = 0; o < FHID; ++o) acc[o] = fmaf(xs, wrow[o], acc[o]);
        }
    }

    int row = rowbase + t;
    if (row >= n) return;
    float dv = dinv[row];
    float4* gp = reinterpret_cast<float4*>(g + (size_t)row * FHID);
#pragma unroll
    for (int q = 0; q < FHID / 4; ++q) {
        float4 v;
        v.x = acc[4 * q + 0] * dv;
        v.y = acc[4 * q + 1] * dv;
        v.z = acc[4 * q + 2] * dv;
        v.w = acc[4 * q + 3] * dv;
        gp[q] = v;
    }
}

// ---------------- CSR aggregate: one wave per node ----------------
// lane = k*16 + c : k in [0,4) edge-group, c in [0,16) channel
// LAYER 1: out = relu(sum*dinv + b1) * dinv    (ready as next layer's messages)
// LAYER 2: out = sum*dinv                      (q, consumed by finish2)

template <int LAYER>
__global__ void k_aggregate(const int* __restrict__ row, const int* __restrict__ cnt,
                            const int* __restrict__ srcs, const float* __restrict__ gin,
                            const float* __restrict__ dinv, const float* __restrict__ b1,
                            float* __restrict__ gout, int n) {
    int wid = (int)(((long long)blockIdx.x * blockDim.x + threadIdx.x) >> 6);
    if (wid >= n) return;
    int lane = threadIdx.x & 63;
    int k = lane >> 4, c = lane & 15;

    // self-loop contribution on group 0
    float acc = (k == 0) ? gin[(size_t)wid * FHID + c] : 0.0f;

    int beg = row[wid];
    int end = beg + cnt[wid];
    for (int i = beg + k; i < end; i += 4) {
        int s = srcs[i];
        acc += gin[(size_t)s * FHID + c];
    }
    acc += __shfl_xor(acc, 16);
    acc += __shfl_xor(acc, 32);

    if (k == 0) {
        float dv = dinv[wid];
        float v = acc * dv;
        if (LAYER == 1) v = fmaxf(v + b1[c], 0.0f) * dv;
        gout[(size_t)wid * FHID + c] = v;
    }
}

// ---------------- finish layer 2: out = log_softmax(q @ W2 + b2) ----------------

__global__ __launch_bounds__(256) void k_finish2(const float* __restrict__ q_in,
                                                 const float* __restrict__ W2,
                                                 const float* __restrict__ b2,
                                                 float* __restrict__ out, int n) {
    __shared__ float Wl[FHID * FOUT];
    __shared__ float bl[FOUT];
    for (int i = threadIdx.x; i < FHID * FOUT; i += 256) Wl[i] = W2[i];
    for (int i = threadIdx.x; i < FOUT; i += 256) bl[i] = b2[i];
    __syncthreads();

    int row = blockIdx.x * 256 + threadIdx.x;
    if (row >= n) return;

    float q[FHID];
    const float4* ap = reinterpret_cast<const float4*>(q_in + (size_t)row * FHID);
#pragma unroll
    for (int t = 0; t < FHID / 4; ++t) {
        float4 v = ap[t];
        q[4 * t + 0] = v.x; q[4 * t + 1] = v.y; q[4 * t + 2] = v.z; q[4 * t + 3] = v.w;
    }

    float acc[FOUT];
#pragma unroll
    for (int o = 0; o < FOUT; ++o) acc[o] = bl[o];
#pragma unroll
    for (int k = 0; k < FHID; ++k) {
        float qs = q[k];
        const float* wrow = &Wl[k * FOUT];
#pragma unroll
        for (int o = 0; o < FOUT; ++o) acc[o] = fmaf(qs, wrow[o], acc[o]);
    }

    float m = acc[0];
#pragma unroll
    for (int o = 1; o < FOUT; ++o) m = fmaxf(m, acc[o]);
    float ssum = 0.0f;
#pragma unroll
    for (int o = 0; o < FOUT; ++o) ssum += expf(acc[o] - m);
    float lse = m + logf(ssum);

    float4* op = reinterpret_cast<float4*>(out + (size_t)row * FOUT);
#pragma unroll
    for (int t = 0; t < FOUT / 4; ++t) {
        float4 v;
        v.x = acc[4 * t + 0] - lse;
        v.y = acc[4 * t + 1] - lse;
        v.z = acc[4 * t + 2] - lse;
        v.w = acc[4 * t + 3] - lse;
        op[t] = v;
    }
}

// ---------------- launch ----------------

extern "C" void kernel_launch(void* const* d_in, const int* in_sizes, int n_in,
                              void* d_out, int out_size, void* d_ws, size_t ws_size,
                              hipStream_t stream) {
    const float* x  = (const float*)d_in[0];
    const int*   ei = (const int*)d_in[1];
    const float* W1 = (const float*)d_in[2];
    const float* b1 = (const float*)d_in[3];
    const float* W2 = (const float*)d_in[4];
    const float* b2 = (const float*)d_in[5];

    const int fh = in_sizes[3];              // 16
    const int fi = in_sizes[2] / fh;         // 512
    const int n  = in_sizes[0] / fi;         // 100000
    const int E  = in_sizes[1] / 2;          // 3200000
    (void)n_in; (void)out_size; (void)ws_size;

    const int* src = ei;
    const int* dst = ei + E;

    // workspace layout
    char* w = (char*)d_ws;
    int*   cnt         = (int*)w;                 w += (size_t)n * 4;
    int*   rowp        = (int*)w;                 w += (size_t)n * 4;
    int*   cursor      = (int*)w;                 w += (size_t)n * 4;
    int*   srcs_sorted = (int*)w;                 w += (size_t)E * 4;
    float* dinv        = (float*)w;               w += (size_t)n * 4;
    float* g           = (float*)w;               w += (size_t)n * FHID * 4;
    float* p           = (float*)w;               /* w += n*FHID*4 */
    float* q           = g;                       // layer-2 result reuses g

    float* out = (float*)d_out;

    const int TB = 256;
    const int nb_e = (E + TB - 1) / TB;
    const int nb_n = (n + TB - 1) / TB;
    const int nb_g = (n + 127) / 128;
    const int nb_w = (int)(((long long)n * 64 + TB - 1) / TB);

    hipMemsetAsync(cnt, 0, (size_t)n * 4, stream);
    k_count<<<nb_e, TB, 0, stream>>>(dst, cnt, E);
    k_scan<<<1, 1024, 0, stream>>>(cnt, rowp, cursor, dinv, n);
    k_fill<<<nb_e, TB, 0, stream>>>(src, dst, cursor, srcs_sorted, E);

    k_gemm1<<<nb_g, 128, 0, stream>>>(x, W1, dinv, g, n);
    k_aggregate<1><<<nb_w, TB, 0, stream>>>(rowp, cnt, srcs_sorted, g, dinv, b1, p, n);
    k_aggregate<2><<<nb_w, TB, 0, stream>>>(rowp, cnt, srcs_sorted, p, dinv, b1, q, n);
    k_finish2<<<nb_n, TB, 0, stream>>>(q, W2, b2, out, n);
}